// Round 1
// baseline (444.628 us; speedup 1.0000x reference)
//
#include <hip/hip_runtime.h>
#include <cstdint>
#include <cstddef>

#define N_NODES 50000
#define N_EDGES 800000
#define DIM 64
#define NREL 8

__device__ __forceinline__ float warp_sum64(float v) {
  #pragma unroll
  for (int m = 32; m >= 1; m >>= 1) v += __shfl_xor(v, m, 64);
  return v;
}

// Wa2[r,d] = sum_e W[r,d,e] * a[r, D+e]
__global__ void k_wa2(const float* __restrict__ W, const float* __restrict__ a,
                      float* __restrict__ Wa2) {
  int r = blockIdx.x;
  int d = threadIdx.x;
  const float* Wr = W + (size_t)r * DIM * DIM + (size_t)d * DIM;
  const float* ar = a + (size_t)r * 2 * DIM + DIM;
  float acc = 0.f;
  #pragma unroll
  for (int e = 0; e < DIM; ++e) acc += Wr[e] * ar[e];
  Wa2[r * DIM + d] = acc;
}

// ha1[n,r] = h[n]·a[r,:D]   hw2[n,r] = h[n]·Wa2[r]
__global__ void k_tables(const float* __restrict__ h, const float* __restrict__ a,
                         const float* __restrict__ Wa2,
                         float* __restrict__ ha1, float* __restrict__ hw2) {
  int node = blockIdx.x * 4 + (threadIdx.x >> 6);
  int lane = threadIdx.x & 63;
  float hv = h[(size_t)node * DIM + lane];
  #pragma unroll
  for (int r = 0; r < NREL; ++r) {
    float p1 = hv * a[r * 2 * DIM + lane];
    float p2 = hv * Wa2[r * DIM + lane];
    p1 = warp_sum64(p1);
    p2 = warp_sum64(p2);
    if (lane == 0) {
      ha1[(size_t)node * NREL + r] = p1;
      hw2[(size_t)node * NREL + r] = p2;
    }
  }
}

__global__ void k_hist(const int* __restrict__ dst, int* __restrict__ deg) {
  int e = blockIdx.x * 256 + threadIdx.x;
  if (e < N_EDGES) atomicAdd(&deg[dst[e]], 1);
}

// single-block exclusive scan of deg[0..N) -> rowstart, cursor; rowstart[N]=E
__global__ void k_scan(const int* __restrict__ deg, int* __restrict__ rowstart,
                       int* __restrict__ cursor) {
  __shared__ int lds[1024];
  const int CH = (N_NODES + 1023) / 1024;  // 49
  int t = threadIdx.x;
  int beg = t * CH;
  int fin = beg + CH; if (fin > N_NODES) fin = N_NODES;
  int s = 0;
  for (int i = beg; i < fin; ++i) s += deg[i];
  lds[t] = s;
  __syncthreads();
  for (int off = 1; off < 1024; off <<= 1) {
    int v = (t >= off) ? lds[t - off] : 0;
    __syncthreads();
    lds[t] += v;
    __syncthreads();
  }
  int run = lds[t] - s;  // exclusive prefix of this chunk
  for (int i = beg; i < fin; ++i) {
    rowstart[i] = run;
    cursor[i] = run;
    run += deg[i];
  }
  if (t == 0) rowstart[N_NODES] = N_EDGES;
}

__global__ void k_scatter(const int* __restrict__ src, const int* __restrict__ dst,
                          const int* __restrict__ et, int* __restrict__ cursor,
                          int* __restrict__ srcs, int* __restrict__ ets) {
  int e = blockIdx.x * 256 + threadIdx.x;
  if (e >= N_EDGES) return;
  int d = dst[e];
  int pos = atomicAdd(&cursor[d], 1);
  srcs[pos] = src[e];
  ets[pos] = et[e];
}

// hW[r,n,:] = h[n,:] @ W[r]   (64-row tile per block, W[r] + h tile in LDS)
__global__ __launch_bounds__(256) void k_hw(const float* __restrict__ h,
                                            const float* __restrict__ W,
                                            float* __restrict__ hW) {
  __shared__ float hs[64 * 64];
  __shared__ float ws[64 * 64];
  const int n0 = blockIdx.x * 64;
  const int r = blockIdx.y;
  const float* Wr = W + (size_t)r * DIM * DIM;
  for (int idx = threadIdx.x; idx < 64 * 64; idx += 256) {
    int row = idx >> 6, col = idx & 63;
    int n = n0 + row;
    hs[idx] = (n < N_NODES) ? h[(size_t)n * DIM + col] : 0.f;
    ws[idx] = Wr[idx];  // ws[k*64+d] = W[r][k][d]
  }
  __syncthreads();
  const int d = threadIdx.x & 63;
  const int rg = threadIdx.x >> 6;
  float acc[16];
  #pragma unroll
  for (int i = 0; i < 16; ++i) acc[i] = 0.f;
  #pragma unroll 4
  for (int k = 0; k < 64; ++k) {
    float wv = ws[k * 64 + d];
    #pragma unroll
    for (int i = 0; i < 16; ++i) acc[i] += hs[(rg * 16 + i) * 64 + k] * wv;
  }
  #pragma unroll
  for (int i = 0; i < 16; ++i) {
    int n = n0 + rg * 16 + i;
    if (n < N_NODES) hW[((size_t)r * N_NODES + n) * DIM + d] = acc[i];
  }
}

// one wave per dst node: fused logits + softmax (no max-subtraction) + weighted
// reduce + residual epilogue. No atomics.
__global__ void k_fused(const float* __restrict__ h, const float* __restrict__ hW,
                        const float* __restrict__ ha1, const float* __restrict__ hw2,
                        const int* __restrict__ rowstart, const int* __restrict__ srcs,
                        const int* __restrict__ ets, const float* __restrict__ dmask,
                        float* __restrict__ out) {
  int node = blockIdx.x * 4 + (threadIdx.x >> 6);
  int lane = threadIdx.x & 63;
  float hv = h[(size_t)node * DIM + lane];
  int s = rowstart[node];
  int e = rowstart[node + 1];
  float acc = 0.f, den = 0.f;
  for (int j = s; j < e; ++j) {
    int sv = srcs[j];
    int rv = ets[j];
    float lg = ha1[(size_t)node * NREL + rv] + hw2[(size_t)sv * NREL + rv];
    lg = lg > 0.f ? lg : 0.2f * lg;
    float w = __expf(lg);
    den += w;
    acc += w * hW[((size_t)rv * N_NODES + sv) * DIM + lane];
  }
  out[(size_t)node * DIM + lane] = hv + acc / (den + 1e-9f) * dmask[lane];
}

extern "C" void kernel_launch(void* const* d_in, const int* in_sizes, int n_in,
                              void* d_out, int out_size, void* d_ws, size_t ws_size,
                              hipStream_t stream) {
  const float* h = (const float*)d_in[0];
  const float* W = (const float*)d_in[1];
  const float* a = (const float*)d_in[2];
  const float* dmask = (const float*)d_in[3];
  const int* src = (const int*)d_in[4];
  const int* dst = (const int*)d_in[5];
  const int* et = (const int*)d_in[6];
  float* out = (float*)d_out;

  char* ws = (char*)d_ws;
  size_t off = 0;
  auto alloc = [&](size_t bytes) {
    void* p = ws + off;
    off += (bytes + 255) & ~(size_t)255;
    return p;
  };
  float* hWbuf = (float*)alloc((size_t)NREL * N_NODES * DIM * 4);  // 102.4 MB
  float* ha1 = (float*)alloc((size_t)N_NODES * NREL * 4);
  float* hw2 = (float*)alloc((size_t)N_NODES * NREL * 4);
  float* Wa2 = (float*)alloc(NREL * DIM * 4);
  int* deg = (int*)alloc(N_NODES * 4);
  int* rowstart = (int*)alloc((N_NODES + 1) * 4);
  int* cursor = (int*)alloc(N_NODES * 4);
  int* srcs = (int*)alloc(N_EDGES * 4);
  int* ets = (int*)alloc(N_EDGES * 4);
  (void)off; (void)ws_size;

  hipMemsetAsync(deg, 0, N_NODES * 4, stream);
  k_wa2<<<NREL, DIM, 0, stream>>>(W, a, Wa2);
  k_tables<<<N_NODES / 4, 256, 0, stream>>>(h, a, Wa2, ha1, hw2);
  k_hist<<<(N_EDGES + 255) / 256, 256, 0, stream>>>(dst, deg);
  k_scan<<<1, 1024, 0, stream>>>(deg, rowstart, cursor);
  k_scatter<<<(N_EDGES + 255) / 256, 256, 0, stream>>>(src, dst, et, cursor, srcs, ets);
  k_hw<<<dim3((N_NODES + 63) / 64, NREL), 256, 0, stream>>>(h, W, hWbuf);
  k_fused<<<N_NODES / 4, 256, 0, stream>>>(h, hWbuf, ha1, hw2, rowstart, srcs, ets,
                                           dmask, out);
}

// Round 2
// 294.790 us; speedup vs baseline: 1.5083x; 1.5083x over previous
//
#include <hip/hip_runtime.h>
#include <cstdint>
#include <cstddef>

#define N_NODES 50000
#define N_EDGES 800000
#define DIM 64
#define NREL 8
#define NBLK 782                 // ceil(N_NODES/64)
#define NPAD (NBLK * 64)         // 50048
#define SCAN_B 196               // ceil(N_NODES/256)

typedef unsigned short u16;
typedef unsigned int u32;
typedef float f32x4 __attribute__((ext_vector_type(4)));
typedef short bf16x8 __attribute__((ext_vector_type(8)));

__device__ __forceinline__ u16 f2b(float f) {
  union { float f; u32 u; } c; c.f = f;
  u32 u = c.u;
  return (u16)((u + 0x7fffu + ((u >> 16) & 1u)) >> 16);  // RNE
}
__device__ __forceinline__ float b2f(u16 v) {
  union { u32 u; float f; } c; c.u = ((u32)v) << 16;
  return c.f;
}

__device__ __forceinline__ float warp_sum64(float v) {
  #pragma unroll
  for (int m = 32; m >= 1; m >>= 1) v += __shfl_xor(v, m, 64);
  return v;
}

// ---- casts -----------------------------------------------------------------
__global__ void k_cast_h(const float* __restrict__ h, u16* __restrict__ hb) {
  size_t i4 = (size_t)blockIdx.x * 256 + threadIdx.x;
  size_t base = i4 * 4;
  if (base >= (size_t)NPAD * DIM) return;
  size_t row = base >> 6;
  u16 o[4];
  if (row < N_NODES) {
    float4 v = *(const float4*)(h + base);
    o[0] = f2b(v.x); o[1] = f2b(v.y); o[2] = f2b(v.z); o[3] = f2b(v.w);
  } else {
    o[0] = o[1] = o[2] = o[3] = 0;
  }
  uint2 s; s.x = (u32)o[0] | ((u32)o[1] << 16); s.y = (u32)o[2] | ((u32)o[3] << 16);
  *(uint2*)(hb + base) = s;
}

// WbT[r][d][k] = W[r][k][d]  (bf16, transposed so A-frag loads are contiguous)
__global__ void k_cast_wt(const float* __restrict__ W, u16* __restrict__ WbT) {
  int r = blockIdx.x;
  for (int idx = threadIdx.x; idx < DIM * DIM; idx += 256) {
    int d = idx >> 6, k = idx & 63;
    WbT[((size_t)r * DIM + d) * DIM + k] = f2b(W[((size_t)r * DIM + k) * DIM + d]);
  }
}

// ---- tiny precomputes (exact f32 on the logit path) ------------------------
// Wa2[r,d] = sum_e W[r,d,e] * a[r, D+e]
__global__ void k_wa2(const float* __restrict__ W, const float* __restrict__ a,
                      float* __restrict__ Wa2) {
  int r = blockIdx.x;
  int d = threadIdx.x;
  const float* Wr = W + (size_t)r * DIM * DIM + (size_t)d * DIM;
  const float* ar = a + (size_t)r * 2 * DIM + DIM;
  float acc = 0.f;
  #pragma unroll
  for (int e = 0; e < DIM; ++e) acc += Wr[e] * ar[e];
  Wa2[r * DIM + d] = acc;
}

// ha1[n,r] = h[n]·a[r,:D]   hw2[n,r] = h[n]·Wa2[r]
__global__ void k_tables(const float* __restrict__ h, const float* __restrict__ a,
                         const float* __restrict__ Wa2,
                         float* __restrict__ ha1, float* __restrict__ hw2) {
  int node = blockIdx.x * 4 + (threadIdx.x >> 6);
  int lane = threadIdx.x & 63;
  float hv = h[(size_t)node * DIM + lane];
  #pragma unroll
  for (int r = 0; r < NREL; ++r) {
    float p1 = hv * a[r * 2 * DIM + lane];
    float p2 = hv * Wa2[r * DIM + lane];
    p1 = warp_sum64(p1);
    p2 = warp_sum64(p2);
    if (lane == 0) {
      ha1[(size_t)node * NREL + r] = p1;
      hw2[(size_t)node * NREL + r] = p2;
    }
  }
}

// ---- CSR build -------------------------------------------------------------
__global__ void k_hist(const int* __restrict__ dst, int* __restrict__ deg) {
  int e = blockIdx.x * 256 + threadIdx.x;
  if (e < N_EDGES) atomicAdd(&deg[dst[e]], 1);
}

// block-local exclusive scan of 256 deg entries; totals to bsum
__global__ void k_scan1(const int* __restrict__ deg, int* __restrict__ rowstart,
                        int* __restrict__ bsum) {
  __shared__ int lds[256];
  int t = threadIdx.x;
  int i = blockIdx.x * 256 + t;
  int v = (i < N_NODES) ? deg[i] : 0;
  lds[t] = v;
  __syncthreads();
  #pragma unroll
  for (int off = 1; off < 256; off <<= 1) {
    int tv = (t >= off) ? lds[t - off] : 0;
    __syncthreads();
    lds[t] += tv;
    __syncthreads();
  }
  if (i < N_NODES) rowstart[i] = lds[t] - v;  // exclusive, block-local
  if (t == 255) bsum[blockIdx.x] = lds[255];
}

__global__ void k_scan2(const int* __restrict__ bsum, int* __restrict__ boff) {
  __shared__ int lds[256];
  int t = threadIdx.x;
  int v = (t < SCAN_B) ? bsum[t] : 0;
  lds[t] = v;
  __syncthreads();
  #pragma unroll
  for (int off = 1; off < 256; off <<= 1) {
    int tv = (t >= off) ? lds[t - off] : 0;
    __syncthreads();
    lds[t] += tv;
    __syncthreads();
  }
  if (t < SCAN_B) boff[t] = lds[t] - v;  // exclusive
}

__global__ void k_scan3(int* __restrict__ rowstart, const int* __restrict__ boff,
                        int* __restrict__ cursor) {
  int t = threadIdx.x;
  int i = blockIdx.x * 256 + t;
  if (i < N_NODES) {
    int v = rowstart[i] + boff[blockIdx.x];
    rowstart[i] = v;
    cursor[i] = v;
  }
  if (blockIdx.x == 0 && t == 0) rowstart[N_NODES] = N_EDGES;
}

// packed edge record: (etype << 16) | src   (src < 50000 < 2^16, et < 8)
__global__ void k_scatter(const int* __restrict__ src, const int* __restrict__ dst,
                          const int* __restrict__ et, int* __restrict__ cursor,
                          int* __restrict__ epk) {
  int e = blockIdx.x * 256 + threadIdx.x;
  if (e >= N_EDGES) return;
  int d = dst[e];
  int pos = atomicAdd(&cursor[d], 1);
  epk[pos] = (et[e] << 16) | src[e];
}

// ---- hW = h @ W_r  via MFMA (computed transposed: D'[d][n] = W^T · h^T) ----
// Per block: 64 nodes, all 8 relations (h fetched once). Per wave: 16 nodes.
// A = WbT rows (M = d, K = k), B = hb rows (N = node, K = k).
// C layout (verified m89): col = lane&15 -> node, row = (lane>>4)*4+reg -> d,
// so each lane's 4 accs are contiguous in d -> packed 8B bf16 store.
__global__ __launch_bounds__(256) void k_hw(const u16* __restrict__ hb,
                                            const u16* __restrict__ WbT,
                                            u16* __restrict__ hW) {
  const int wv = threadIdx.x >> 6;
  const int lane = threadIdx.x & 63;
  const int l15 = lane & 15;
  const int kg = lane >> 4;  // 0..3: K-group of 8
  const int n = blockIdx.x * 64 + wv * 16 + l15;
  const bf16x8* hrow = (const bf16x8*)(hb + (size_t)n * DIM);
  const bf16x8 b0 = hrow[kg];      // k = kg*8 + j
  const bf16x8 b1 = hrow[4 + kg];  // k = 32 + kg*8 + j
  const bool ok = (n < N_NODES);
  #pragma unroll
  for (int r = 0; r < NREL; ++r) {
    #pragma unroll
    for (int dt = 0; dt < 4; ++dt) {
      const int d = dt * 16 + l15;
      const bf16x8* wrow = (const bf16x8*)(WbT + ((size_t)r * DIM + d) * DIM);
      f32x4 acc = {0.f, 0.f, 0.f, 0.f};
      acc = __builtin_amdgcn_mfma_f32_16x16x32_bf16(wrow[kg], b0, acc, 0, 0, 0);
      acc = __builtin_amdgcn_mfma_f32_16x16x32_bf16(wrow[4 + kg], b1, acc, 0, 0, 0);
      if (ok) {
        uint2 s;
        s.x = (u32)f2b(acc[0]) | ((u32)f2b(acc[1]) << 16);
        s.y = (u32)f2b(acc[2]) | ((u32)f2b(acc[3]) << 16);
        *(uint2*)(hW + ((size_t)r * N_NODES + n) * DIM + dt * 16 + kg * 4) = s;
      }
    }
  }
}

// ---- fused softmax + weighted reduce + residual (wave per dst node) --------
__global__ void k_fused(const float* __restrict__ h, const u16* __restrict__ hW,
                        const float* __restrict__ ha1, const float* __restrict__ hw2,
                        const int* __restrict__ rowstart, const int* __restrict__ epk,
                        const float* __restrict__ dmask, float* __restrict__ out) {
  int node = blockIdx.x * 4 + (threadIdx.x >> 6);
  int lane = threadIdx.x & 63;
  float hv = h[(size_t)node * DIM + lane];
  int s = rowstart[node];
  int e = rowstart[node + 1];
  float acc = 0.f, den = 0.f;
  for (int j = s; j < e; ++j) {
    int p = epk[j];
    int sv = p & 0xffff;
    int rv = p >> 16;
    float lg = ha1[(size_t)node * NREL + rv] + hw2[(size_t)sv * NREL + rv];
    lg = lg > 0.f ? lg : 0.2f * lg;
    float w = __expf(lg);
    den += w;
    acc += w * b2f(hW[((size_t)rv * N_NODES + sv) * DIM + lane]);
  }
  out[(size_t)node * DIM + lane] = hv + acc / (den + 1e-9f) * dmask[lane];
}

extern "C" void kernel_launch(void* const* d_in, const int* in_sizes, int n_in,
                              void* d_out, int out_size, void* d_ws, size_t ws_size,
                              hipStream_t stream) {
  const float* h = (const float*)d_in[0];
  const float* W = (const float*)d_in[1];
  const float* a = (const float*)d_in[2];
  const float* dmask = (const float*)d_in[3];
  const int* src = (const int*)d_in[4];
  const int* dst = (const int*)d_in[5];
  const int* et = (const int*)d_in[6];
  float* out = (float*)d_out;

  char* ws = (char*)d_ws;
  size_t off = 0;
  auto alloc = [&](size_t bytes) {
    void* p = ws + off;
    off += (bytes + 255) & ~(size_t)255;
    return p;
  };
  u16* hWbuf = (u16*)alloc((size_t)NREL * N_NODES * DIM * 2);  // 51.2 MB
  u16* hb = (u16*)alloc((size_t)NPAD * DIM * 2);               // 6.4 MB
  u16* WbT = (u16*)alloc((size_t)NREL * DIM * DIM * 2);        // 64 KB
  float* ha1 = (float*)alloc((size_t)N_NODES * NREL * 4);
  float* hw2 = (float*)alloc((size_t)N_NODES * NREL * 4);
  float* Wa2 = (float*)alloc(NREL * DIM * 4);
  int* deg = (int*)alloc(N_NODES * 4);
  int* rowstart = (int*)alloc((N_NODES + 1) * 4);
  int* cursor = (int*)alloc(N_NODES * 4);
  int* bsum = (int*)alloc(SCAN_B * 4);
  int* boff = (int*)alloc(SCAN_B * 4);
  int* epk = (int*)alloc((size_t)N_EDGES * 4);
  (void)off; (void)ws_size;

  hipMemsetAsync(deg, 0, N_NODES * 4, stream);
  k_cast_h<<<(NPAD * DIM / 4 + 255) / 256, 256, 0, stream>>>(h, hb);
  k_cast_wt<<<NREL, 256, 0, stream>>>(W, WbT);
  k_wa2<<<NREL, DIM, 0, stream>>>(W, a, Wa2);
  k_tables<<<N_NODES / 4, 256, 0, stream>>>(h, a, Wa2, ha1, hw2);
  k_hist<<<(N_EDGES + 255) / 256, 256, 0, stream>>>(dst, deg);
  k_scan1<<<SCAN_B, 256, 0, stream>>>(deg, rowstart, bsum);
  k_scan2<<<1, 256, 0, stream>>>(bsum, boff);
  k_scan3<<<SCAN_B, 256, 0, stream>>>(rowstart, boff, cursor);
  k_scatter<<<(N_EDGES + 255) / 256, 256, 0, stream>>>(src, dst, et, cursor, epk);
  k_hw<<<NBLK, 256, 0, stream>>>(hb, WbT, hWbuf);
  k_fused<<<N_NODES / 4, 256, 0, stream>>>(h, hWbuf, ha1, hw2, rowstart, epk,
                                           dmask, out);
}

// Round 3
// 193.514 us; speedup vs baseline: 2.2977x; 1.5234x over previous
//
#include <hip/hip_runtime.h>
#include <cstdint>
#include <cstddef>

#define N_NODES 50000
#define N_EDGES 800000
#define DIM 64
#define NREL 8
#define NBLK 782                 // ceil(N_NODES/64)
#define NPAD (NBLK * 64)         // 50048
#define SCAN_B 196               // ceil(N_NODES/256)

typedef unsigned short u16;
typedef unsigned int u32;
typedef float f32x4 __attribute__((ext_vector_type(4)));
typedef short bf16x8 __attribute__((ext_vector_type(8)));

__device__ __forceinline__ u16 f2b(float f) {
  union { float f; u32 u; } c; c.f = f;
  u32 u = c.u;
  return (u16)((u + 0x7fffu + ((u >> 16) & 1u)) >> 16);  // RNE
}
__device__ __forceinline__ float b2f(u16 v) {
  union { u32 u; float f; } c; c.u = ((u32)v) << 16;
  return c.f;
}

// ---- casts -----------------------------------------------------------------
__global__ void k_cast_h(const float* __restrict__ h, u16* __restrict__ hb) {
  size_t i4 = (size_t)blockIdx.x * 256 + threadIdx.x;
  size_t base = i4 * 4;
  if (base >= (size_t)NPAD * DIM) return;
  size_t row = base >> 6;
  u16 o[4];
  if (row < N_NODES) {
    float4 v = *(const float4*)(h + base);
    o[0] = f2b(v.x); o[1] = f2b(v.y); o[2] = f2b(v.z); o[3] = f2b(v.w);
  } else {
    o[0] = o[1] = o[2] = o[3] = 0;
  }
  uint2 s; s.x = (u32)o[0] | ((u32)o[1] << 16); s.y = (u32)o[2] | ((u32)o[3] << 16);
  *(uint2*)(hb + base) = s;
}

// block r: WbT[r][d][k] = W[r][k][d] (bf16) ; Wa2[r,d] = sum_e W[r,d,e]*a[r,D+e]
__global__ void k_cast_wt(const float* __restrict__ W, const float* __restrict__ a,
                          u16* __restrict__ WbT, float* __restrict__ Wa2) {
  int r = blockIdx.x;
  for (int idx = threadIdx.x; idx < DIM * DIM; idx += 256) {
    int d = idx >> 6, k = idx & 63;
    WbT[((size_t)r * DIM + d) * DIM + k] = f2b(W[((size_t)r * DIM + k) * DIM + d]);
  }
  if (threadIdx.x < DIM) {
    int d = threadIdx.x;
    const float* Wr = W + (size_t)r * DIM * DIM + (size_t)d * DIM;
    const float* ar = a + (size_t)r * 2 * DIM + DIM;
    float acc = 0.f;
    #pragma unroll
    for (int e = 0; e < DIM; ++e) acc += Wr[e] * ar[e];
    Wa2[r * DIM + d] = acc;
  }
}

// Tb[16][64] bf16: rows 0..7 = a[r,:D] (dst side), rows 8..15 = Wa2[r] (src side)
__global__ void k_prep_tbl(const float* __restrict__ a, const float* __restrict__ Wa2,
                           u16* __restrict__ Tb) {
  int idx = threadIdx.x * 4;  // 256 threads * 4 = 1024
  int row = idx >> 6;
  int k = idx & 63;
  #pragma unroll
  for (int j = 0; j < 4; ++j) {
    float v = (row < 8) ? a[row * 2 * DIM + k + j] : Wa2[(row - 8) * DIM + k + j];
    Tb[row * DIM + k + j] = f2b(v);
  }
}

// ---- CSR build (4 edges/thread for MLP) ------------------------------------
__global__ void k_hist(const int* __restrict__ dst, int* __restrict__ deg) {
  int i = blockIdx.x * 256 + threadIdx.x;
  if (i >= N_EDGES / 4) return;
  int4 d4 = ((const int4*)dst)[i];
  atomicAdd(&deg[d4.x], 1);
  atomicAdd(&deg[d4.y], 1);
  atomicAdd(&deg[d4.z], 1);
  atomicAdd(&deg[d4.w], 1);
}

__global__ void k_scan1(const int* __restrict__ deg, int* __restrict__ rowstart,
                        int* __restrict__ bsum) {
  __shared__ int lds[256];
  int t = threadIdx.x;
  int i = blockIdx.x * 256 + t;
  int v = (i < N_NODES) ? deg[i] : 0;
  lds[t] = v;
  __syncthreads();
  #pragma unroll
  for (int off = 1; off < 256; off <<= 1) {
    int tv = (t >= off) ? lds[t - off] : 0;
    __syncthreads();
    lds[t] += tv;
    __syncthreads();
  }
  if (i < N_NODES) rowstart[i] = lds[t] - v;
  if (t == 255) bsum[blockIdx.x] = lds[255];
}

__global__ void k_scan2(const int* __restrict__ bsum, int* __restrict__ boff) {
  __shared__ int lds[256];
  int t = threadIdx.x;
  int v = (t < SCAN_B) ? bsum[t] : 0;
  lds[t] = v;
  __syncthreads();
  #pragma unroll
  for (int off = 1; off < 256; off <<= 1) {
    int tv = (t >= off) ? lds[t - off] : 0;
    __syncthreads();
    lds[t] += tv;
    __syncthreads();
  }
  if (t < SCAN_B) boff[t] = lds[t] - v;
}

__global__ void k_scan3(int* __restrict__ rowstart, const int* __restrict__ boff,
                        int* __restrict__ cursor) {
  int t = threadIdx.x;
  int i = blockIdx.x * 256 + t;
  if (i < N_NODES) {
    int v = rowstart[i] + boff[blockIdx.x];
    rowstart[i] = v;
    cursor[i] = v;
  }
  if (blockIdx.x == 0 && t == 0) rowstart[N_NODES] = N_EDGES;
}

// packed edge record: (etype << 16) | src
__global__ void k_scatter(const int* __restrict__ src, const int* __restrict__ dst,
                          const int* __restrict__ et, int* __restrict__ cursor,
                          int* __restrict__ epk) {
  int i = blockIdx.x * 256 + threadIdx.x;
  if (i >= N_EDGES / 4) return;
  int4 s4 = ((const int4*)src)[i];
  int4 d4 = ((const int4*)dst)[i];
  int4 t4 = ((const int4*)et)[i];
  int p0 = atomicAdd(&cursor[d4.x], 1);
  int p1 = atomicAdd(&cursor[d4.y], 1);
  int p2 = atomicAdd(&cursor[d4.z], 1);
  int p3 = atomicAdd(&cursor[d4.w], 1);
  epk[p0] = (t4.x << 16) | s4.x;
  epk[p1] = (t4.y << 16) | s4.y;
  epk[p2] = (t4.z << 16) | s4.z;
  epk[p3] = (t4.w << 16) | s4.w;
}

// ---- hW = h @ W_r via MFMA + fused logit-table GEMM ------------------------
// Per block: 64 nodes, all 8 relations + tbl. Per wave: 16 nodes.
// C layout: col=lane&15 -> node(B idx), row=(lane>>4)*4+reg -> A idx.
__global__ __launch_bounds__(256) void k_hw(const u16* __restrict__ hb,
                                            const u16* __restrict__ WbT,
                                            const u16* __restrict__ Tb,
                                            u16* __restrict__ hW,
                                            float* __restrict__ tbl) {
  const int wv = threadIdx.x >> 6;
  const int lane = threadIdx.x & 63;
  const int l15 = lane & 15;
  const int kg = lane >> 4;  // 0..3
  const int n = blockIdx.x * 64 + wv * 16 + l15;
  const bf16x8* hrow = (const bf16x8*)(hb + (size_t)n * DIM);
  const bf16x8 b0 = hrow[kg];
  const bf16x8 b1 = hrow[4 + kg];
  const bool ok = (n < N_NODES);
  // logit tables: tbl[n][t] = h[n] . Tb[t]
  {
    const bf16x8* trow = (const bf16x8*)(Tb + (size_t)l15 * DIM);
    f32x4 acc = {0.f, 0.f, 0.f, 0.f};
    acc = __builtin_amdgcn_mfma_f32_16x16x32_bf16(trow[kg], b0, acc, 0, 0, 0);
    acc = __builtin_amdgcn_mfma_f32_16x16x32_bf16(trow[4 + kg], b1, acc, 0, 0, 0);
    if (ok) *(f32x4*)(tbl + (size_t)n * 16 + kg * 4) = acc;
  }
  #pragma unroll
  for (int r = 0; r < NREL; ++r) {
    #pragma unroll
    for (int dt = 0; dt < 4; ++dt) {
      const int d = dt * 16 + l15;
      const bf16x8* wrow = (const bf16x8*)(WbT + ((size_t)r * DIM + d) * DIM);
      f32x4 acc = {0.f, 0.f, 0.f, 0.f};
      acc = __builtin_amdgcn_mfma_f32_16x16x32_bf16(wrow[kg], b0, acc, 0, 0, 0);
      acc = __builtin_amdgcn_mfma_f32_16x16x32_bf16(wrow[4 + kg], b1, acc, 0, 0, 0);
      if (ok) {
        uint2 s;
        s.x = (u32)f2b(acc[0]) | ((u32)f2b(acc[1]) << 16);
        s.y = (u32)f2b(acc[2]) | ((u32)f2b(acc[3]) << 16);
        *(uint2*)(hW + ((size_t)r * N_NODES + n) * DIM + dt * 16 + kg * 4) = s;
      }
    }
  }
}

// ---- fused softmax+reduce: wave per node, 4 edges/iter, 16 lanes/edge ------
__global__ void k_fused(const float* __restrict__ h, const u16* __restrict__ hW,
                        const float* __restrict__ tbl,
                        const int* __restrict__ rowstart, const int* __restrict__ epk,
                        const float* __restrict__ dmask, float* __restrict__ out) {
  const int node = blockIdx.x * 4 + (threadIdx.x >> 6);
  const int lane = threadIdx.x & 63;
  const int g = lane >> 4;   // edge slot 0..3
  const int l = lane & 15;   // d-quad index
  const int s = rowstart[node];
  const int e = rowstart[node + 1];
  float ax = 0.f, ay = 0.f, az = 0.f, aw = 0.f, den = 0.f;
  for (int j = s; j < e; j += 4) {
    const int idx = j + g;
    const bool valid = idx < e;
    const int p = valid ? epk[idx] : 0;
    const int sv = p & 0xffff;
    const int rv = p >> 16;
    float lg = tbl[(size_t)node * 16 + rv] + tbl[(size_t)sv * 16 + 8 + rv];
    lg = lg > 0.f ? lg : 0.2f * lg;
    const float w = valid ? __expf(lg) : 0.f;
    den += w;
    uint2 q = {0u, 0u};
    if (valid) q = *(const uint2*)(hW + ((size_t)rv * N_NODES + sv) * DIM + l * 4);
    ax += w * b2f((u16)(q.x & 0xffff));
    ay += w * b2f((u16)(q.x >> 16));
    az += w * b2f((u16)(q.y & 0xffff));
    aw += w * b2f((u16)(q.y >> 16));
  }
  // combine the 4 edge groups (within-group lanes hold identical den)
  #pragma unroll
  for (int m = 16; m <= 32; m <<= 1) {
    ax += __shfl_xor(ax, m, 64);
    ay += __shfl_xor(ay, m, 64);
    az += __shfl_xor(az, m, 64);
    aw += __shfl_xor(aw, m, 64);
    den += __shfl_xor(den, m, 64);
  }
  if (lane < 16) {
    const float4 hv = *(const float4*)(h + (size_t)node * DIM + l * 4);
    const float4 dm = *(const float4*)(dmask + l * 4);
    const float inv = 1.f / (den + 1e-9f);
    float4 o;
    o.x = hv.x + ax * inv * dm.x;
    o.y = hv.y + ay * inv * dm.y;
    o.z = hv.z + az * inv * dm.z;
    o.w = hv.w + aw * inv * dm.w;
    *(float4*)(out + (size_t)node * DIM + l * 4) = o;
  }
}

extern "C" void kernel_launch(void* const* d_in, const int* in_sizes, int n_in,
                              void* d_out, int out_size, void* d_ws, size_t ws_size,
                              hipStream_t stream) {
  const float* h = (const float*)d_in[0];
  const float* W = (const float*)d_in[1];
  const float* a = (const float*)d_in[2];
  const float* dmask = (const float*)d_in[3];
  const int* src = (const int*)d_in[4];
  const int* dst = (const int*)d_in[5];
  const int* et = (const int*)d_in[6];
  float* out = (float*)d_out;

  char* ws = (char*)d_ws;
  size_t off = 0;
  auto alloc = [&](size_t bytes) {
    void* p = ws + off;
    off += (bytes + 255) & ~(size_t)255;
    return p;
  };
  u16* hWbuf = (u16*)alloc((size_t)NREL * N_NODES * DIM * 2);  // 51.2 MB
  u16* hb = (u16*)alloc((size_t)NPAD * DIM * 2);               // 6.4 MB
  u16* WbT = (u16*)alloc((size_t)NREL * DIM * DIM * 2);
  u16* Tb = (u16*)alloc(16 * DIM * 2);
  float* tbl = (float*)alloc((size_t)N_NODES * 16 * 4);        // 3.2 MB
  float* Wa2 = (float*)alloc(NREL * DIM * 4);
  int* deg = (int*)alloc(N_NODES * 4);
  int* rowstart = (int*)alloc((N_NODES + 1) * 4);
  int* cursor = (int*)alloc(N_NODES * 4);
  int* bsum = (int*)alloc(SCAN_B * 4);
  int* boff = (int*)alloc(SCAN_B * 4);
  int* epk = (int*)alloc((size_t)N_EDGES * 4);
  (void)off; (void)ws_size;

  hipMemsetAsync(deg, 0, N_NODES * 4, stream);
  k_cast_h<<<(NPAD * DIM / 4 + 255) / 256, 256, 0, stream>>>(h, hb);
  k_cast_wt<<<NREL, 256, 0, stream>>>(W, a, WbT, Wa2);
  k_prep_tbl<<<1, 256, 0, stream>>>(a, Wa2, Tb);
  k_hist<<<(N_EDGES / 4 + 255) / 256, 256, 0, stream>>>(dst, deg);
  k_scan1<<<SCAN_B, 256, 0, stream>>>(deg, rowstart, bsum);
  k_scan2<<<1, 256, 0, stream>>>(bsum, boff);
  k_scan3<<<SCAN_B, 256, 0, stream>>>(rowstart, boff, cursor);
  k_scatter<<<(N_EDGES / 4 + 255) / 256, 256, 0, stream>>>(src, dst, et, cursor, epk);
  k_hw<<<NBLK, 256, 0, stream>>>(hb, WbT, Tb, hWbuf, tbl);
  k_fused<<<N_NODES / 4, 256, 0, stream>>>(h, hWbuf, tbl, rowstart, epk, dmask, out);
}